// Round 1
// baseline (481.297 us; speedup 1.0000x reference)
//
#include <hip/hip_runtime.h>

// VectorQuantizer forward: N=131072 rows of D=64 vs K=1024 codes.
// Outputs flat fp32: [quantized_st (N*D), loss (1), indices-as-float (N)].

#define NROWS 131072
#define DIM 64
#define KCODES 1024

// loss = q_latent + 0.25 * e_latent; both equal mean((q-x)^2) in fwd
#define LOSS_SCALE (1.25f / ((float)NROWS * (float)DIM))

__global__ __launch_bounds__(256) void e2_kernel(const float* __restrict__ w,
                                                 float* __restrict__ e2) {
    int k = blockIdx.x * blockDim.x + threadIdx.x;
    if (k < KCODES) {
        const float* wk = w + k * DIM;
        float s = 0.f;
#pragma unroll
        for (int d = 0; d < DIM; ++d) s = fmaf(wk[d], wk[d], s);
        e2[k] = s;
    }
}

__global__ __launch_bounds__(256) void vq_kernel(const float* __restrict__ x,
                                                 const float* __restrict__ w,
                                                 const float* __restrict__ e2,
                                                 float* __restrict__ out_q,
                                                 float* __restrict__ out_loss,
                                                 float* __restrict__ out_idx) {
    const int row = blockIdx.x * blockDim.x + threadIdx.x;

    // Load this thread's row into registers (16 x float4)
    float xr[DIM];
    const float4* xv = (const float4*)(x + (size_t)row * DIM);
#pragma unroll
    for (int i = 0; i < DIM / 4; ++i) {
        float4 v = xv[i];
        xr[4 * i + 0] = v.x;
        xr[4 * i + 1] = v.y;
        xr[4 * i + 2] = v.z;
        xr[4 * i + 3] = v.w;
    }

    float x2 = 0.f;
#pragma unroll
    for (int d = 0; d < DIM; ++d) x2 = fmaf(xr[d], xr[d], x2);

    // Scan all K codes; weight addresses are wave-uniform -> scalar loads.
    float best = 3.4e38f;
    int bi = 0;
    for (int k = 0; k < KCODES; ++k) {
        const float* __restrict__ wk = w + k * DIM;
        float dot = 0.f;
#pragma unroll
        for (int d = 0; d < DIM; ++d) dot = fmaf(wk[d], xr[d], dot);
        // mimic reference rounding: (x2 + e2) - 2*dot
        float dist = (x2 + e2[k]) - 2.0f * dot;
        if (dist < best) { best = dist; bi = k; }   // strict < keeps first index
    }

    // Gather winning code, write quantized_st = x + (q - x), accumulate loss
    const float* __restrict__ wb = w + bi * DIM;
    float lsum = 0.f;
    float4* outv = (float4*)(out_q + (size_t)row * DIM);
#pragma unroll
    for (int i = 0; i < DIM / 4; ++i) {
        float q0 = wb[4 * i + 0], q1 = wb[4 * i + 1];
        float q2 = wb[4 * i + 2], q3 = wb[4 * i + 3];
        float d0 = q0 - xr[4 * i + 0];
        float d1 = q1 - xr[4 * i + 1];
        float d2 = q2 - xr[4 * i + 2];
        float d3 = q3 - xr[4 * i + 3];
        lsum = fmaf(d0, d0, lsum);
        lsum = fmaf(d1, d1, lsum);
        lsum = fmaf(d2, d2, lsum);
        lsum = fmaf(d3, d3, lsum);
        float4 o;
        o.x = xr[4 * i + 0] + d0;   // x + (q - x), reference STE rounding
        o.y = xr[4 * i + 1] + d1;
        o.z = xr[4 * i + 2] + d2;
        o.w = xr[4 * i + 3] + d3;
        outv[i] = o;
    }

    out_idx[row] = (float)bi;

    // Reduce loss: wave shuffle -> LDS across 4 waves -> one atomic per block
    for (int off = 32; off > 0; off >>= 1) lsum += __shfl_down(lsum, off, 64);
    __shared__ float red[4];
    const int wid = threadIdx.x >> 6;
    const int lane = threadIdx.x & 63;
    if (lane == 0) red[wid] = lsum;
    __syncthreads();
    if (threadIdx.x == 0) {
        float s = (red[0] + red[1]) + (red[2] + red[3]);
        atomicAdd(out_loss, s * LOSS_SCALE);
    }
}

extern "C" void kernel_launch(void* const* d_in, const int* in_sizes, int n_in,
                              void* d_out, int out_size, void* d_ws, size_t ws_size,
                              hipStream_t stream) {
    const float* x = (const float*)d_in[0];   // [N, D]
    const float* w = (const float*)d_in[1];   // [K, D]

    float* out_q    = (float*)d_out;                      // [N, D]
    float* out_loss = (float*)d_out + (size_t)NROWS * DIM; // [1]
    float* out_idx  = out_loss + 1;                        // [N] as floats

    float* e2 = (float*)d_ws;                              // [K]

    // zero the loss accumulator (d_out is poisoned 0xAA before every launch)
    hipMemsetAsync(out_loss, 0, sizeof(float), stream);

    e2_kernel<<<(KCODES + 255) / 256, 256, 0, stream>>>(w, e2);
    vq_kernel<<<NROWS / 256, 256, 0, stream>>>(x, w, e2, out_q, out_loss, out_idx);
}